// Round 1
// baseline (518.336 us; speedup 1.0000x reference)
//
#include <hip/hip_runtime.h>
#include <math.h>

// Problem constants (from reference): x (B,T,C) fp32
constexpr int Bn = 16;
constexpr int Tn = 8192;
constexpr int Cn = 512;

constexpr float ALPHA    = 0.99f;
constexpr float ONE_M    = 0.01f;     // 1 - ALPHA
constexpr float EPS      = 1e-6f;
constexpr float EMA_INIT = 1e-4f;

// Chunked scan config
constexpr int L   = 128;          // timesteps per chunk
constexpr int NCH = Tn / L;       // 64 chunks
constexpr int G   = 8;            // timesteps per reduction batch in pass 3

// exact alpha^L at compile time (double)
constexpr double cpow(double a, int n) { double r = 1.0; for (int i = 0; i < n; i++) r *= a; return r; }
constexpr float ALPHA_L  = (float)cpow(0.99, L);
constexpr float LN_ALPHA = (float)-0.010050335853501441;  // ln(0.99)

#if __has_builtin(__builtin_amdgcn_rcpf)
__device__ inline float fast_rcp(float x) { return __builtin_amdgcn_rcpf(x); }
#else
__device__ inline float fast_rcp(float x) { return 1.0f / x; }
#endif

// ---------------- Pass 1: per-chunk local scan value (zero incoming state) ----
__global__ __launch_bounds__(512) void pass1_local(const float* __restrict__ x,
                                                   float* __restrict__ carry) {
    const int blk = blockIdx.x;          // b*NCH + j
    const int b = blk >> 6;              // NCH == 64
    const int j = blk & (NCH - 1);
    const int c = threadIdx.x;

    const float* xp = x + ((size_t)(b * Tn + j * L)) * Cn + c;
    float s = 0.0f;
#pragma unroll 8
    for (int i = 0; i < L; i++) {
        float v = xp[(size_t)i * Cn];
        s = ALPHA * s + (ONE_M * v) * v;
    }
    carry[(size_t)blk * Cn + c] = s;
}

// ---------------- Pass 2: scan chunk carries -> incoming state per chunk ------
__global__ __launch_bounds__(256) void pass2_scan(const float* __restrict__ carry,
                                                  float* __restrict__ state) {
    const int idx = blockIdx.x * 256 + threadIdx.x;   // over B*C
    const int b = idx >> 9;                           // Cn == 512
    const int c = idx & (Cn - 1);

    const size_t base = (size_t)b * NCH * Cn + c;
    float s = EMA_INIT;
#pragma unroll
    for (int j = 0; j < NCH; j++) {
        state[base + (size_t)j * Cn] = s;                 // incoming state of chunk j
        s = ALPHA_L * s + carry[base + (size_t)j * Cn];   // propagate across chunk
    }
}

// ---------------- Pass 3: resume scan, normalize, write y ---------------------
__global__ __launch_bounds__(512) void pass3_norm(const float* __restrict__ x,
                                                  const float* __restrict__ state,
                                                  const float* __restrict__ gamma,
                                                  const float* __restrict__ beta,
                                                  float* __restrict__ y) {
    __shared__ float part[2][G][8];      // [buf][timestep-in-batch][wave]

    const int blk  = blockIdx.x;         // b*NCH + j
    const int b    = blk >> 6;
    const int j    = blk & (NCH - 1);
    const int c    = threadIdx.x;
    const int wave = c >> 6;
    const int lane = c & 63;

    float ema = state[(size_t)blk * Cn + c];
    const float gm = gamma[c];
    const float bt = beta[c];

    const int t0 = j * L;                               // 0-based global timestep
    float p = __expf((float)t0 * LN_ALPHA);             // alpha^t0

    float xv[G], gv[G];
    for (int base = 0; base < L; base += G) {
        const int buf = (base / G) & 1;
        const float* xp = x + ((size_t)(b * Tn + t0 + base)) * Cn + c;

#pragma unroll
        for (int i = 0; i < G; i++) xv[i] = xp[(size_t)i * Cn];

#pragma unroll
        for (int i = 0; i < G; i++) {
            const float v = xv[i];
            ema = ALPHA * ema + (ONE_M * v) * v;
            p *= ALPHA;                                  // alpha^(t0+base+i+1)
            const float d = (1.0f - p) + EPS;            // denom + EPS
            const float gq = sqrtf(ema * fast_rcp(d) + EPS);
            gv[i] = gq;
            float r = gq;                                // wave butterfly sum
#pragma unroll
            for (int off = 32; off; off >>= 1) r += __shfl_xor(r, off, 64);
            if (lane == 0) part[buf][i][wave] = r;
        }
        __syncthreads();                                 // partials visible; double-buffer
                                                         // protects WAR across batches
        float* yp = y + ((size_t)(b * Tn + t0 + base)) * Cn + c;
#pragma unroll
        for (int i = 0; i < G; i++) {
            const float4* p4 = (const float4*)part[buf][i];  // same addr all lanes: LDS broadcast
            const float4 u = p4[0], w = p4[1];
            const float s8 = ((u.x + u.y) + (u.z + u.w)) + ((w.x + w.y) + (w.z + w.w));
            const float invm = fast_rcp(s8 * (1.0f / (float)Cn) + EPS);
            const float n = gv[i] * invm;
            const float out = gm * (xv[i] * n) + bt + xv[i];
            __builtin_nontemporal_store(out, yp + (size_t)i * Cn);
        }
    }
}

extern "C" void kernel_launch(void* const* d_in, const int* in_sizes, int n_in,
                              void* d_out, int out_size, void* d_ws, size_t ws_size,
                              hipStream_t stream) {
    const float* x     = (const float*)d_in[0];
    const float* gamma = (const float*)d_in[1];
    const float* beta  = (const float*)d_in[2];
    float* y = (float*)d_out;

    // workspace: carries then states, each B*NCH*C floats (2 MiB each)
    float* carry = (float*)d_ws;
    float* state = carry + (size_t)Bn * NCH * Cn;

    pass1_local<<<Bn * NCH, 512, 0, stream>>>(x, carry);
    pass2_scan<<<(Bn * Cn) / 256, 256, 0, stream>>>(carry, state);
    pass3_norm<<<Bn * NCH, 512, 0, stream>>>(x, state, gamma, beta, y);
}